// Round 1
// 458.718 us; speedup vs baseline: 1.0199x; 1.0199x over previous
//
#include <hip/hip_runtime.h>
#include <math.h>

#define B_ 512
#define S_ 2048
#define E_DIM 64
#define P_DIM 32
#define H_DIM 64
#define CB_STRIDE 68  // 64 pc + mc + sc + ra + pad

typedef short s16x8 __attribute__((ext_vector_type(8)));
typedef float f32x4 __attribute__((ext_vector_type(4)));

__device__ __forceinline__ float wave_reduce_sum(float v) {
#pragma unroll
  for (int m = 32; m >= 1; m >>= 1) v += __shfl_xor(v, m, 64);
  return v;
}

__device__ __forceinline__ float wave_reduce_max(float v) {
#pragma unroll
  for (int m = 32; m >= 1; m >>= 1) v = fmaxf(v, __shfl_xor(v, m, 64));
  return v;
}

__device__ __forceinline__ float tanh_fast(float x) {
  float e = __expf(2.0f * x);
  return 1.0f - 2.0f * __builtin_amdgcn_rcpf(e + 1.0f);
}

// fp32 -> bf16 bits with round-to-nearest-even
__device__ __forceinline__ short bf16b(float x) {
  union { float f; unsigned u; } a;
  a.f = x;
  unsigned r = (a.u + 0x7FFFu + ((a.u >> 16) & 1u)) >> 16;
  return (short)r;
}

// ---------------------------------------------------------------------------
// K1 (MFMA + fused chunk-softmax partials):
//   a[s] = sum_h tanh(c[b,h] + [items|pos]@[We;Wp][:,h]) * z[h]  (as before)
//   then per 128-row chunk: mc = max a, sc = sum exp(a-mc),
//   pc[e] = sum exp(a-mc)*items[s,e] (items are L1/L2-hot), ra = sum raw a.
//   L==0: all rows treated as valid with a=0 (uniform), ra forced 0.
// Writes 68 floats per chunk to chunk_buf; no a_buf, no second items pass.
// ---------------------------------------------------------------------------
__global__ __launch_bounds__(256) void scores_mfma_kernel(
    const float* __restrict__ seq_items, const float* __restrict__ seq_pos,
    const float* __restrict__ target_item, const float* __restrict__ Wp,
    const float* __restrict__ We, const float* __restrict__ Wc,
    const float* __restrict__ bias, const float* __restrict__ z,
    const int* __restrict__ seq_len, float* __restrict__ chunk_buf) {
  const int blk = blockIdx.x;
  const int b = blk >> 4;          // 16 chunks of 128 positions per b
  const int s0 = (blk & 15) << 7;
  const int L = seq_len[b];
  const bool uni = (L == 0);
  if (!uni && s0 >= L) return;  // combine kernel never reads these chunks

  __shared__ s16x8 lds_b[12 * 64];          // 12 KiB: B fragments
  __shared__ float c_part[4 * 64];          // partial c over e-slices
  __shared__ float s_a[128];                // raw scores of this chunk
  __shared__ float s_w[128];                // exp(a - mc)
  __shared__ __align__(16) float s_pc[4 * 64];  // per-wave weighted item sums
  __shared__ float redm[4], reds[4], redr[4];

  const int tid = threadIdx.x;
  const int l = tid & 63;
  const int w = tid >> 6;
  const int cc = l & 15;  // col within 16 (n / h-within-tile; also row m for A)
  const int q = l >> 4;   // quad -> k-chunk (and row-group for C/D)

  // ---- build B fragments: wave w builds frags 3w..3w+2 ----
#pragma unroll
  for (int i = 0; i < 3; ++i) {
    const int f = w * 3 + i;
    const int kstep = f >> 2;
    const int nt = f & 3;
    const float* __restrict__ src =
        (kstep < 2) ? (We + (size_t)(kstep * 32 + q * 8) * H_DIM + nt * 16 + cc)
                    : (Wp + (size_t)(q * 8) * H_DIM + nt * 16 + cc);
    s16x8 v;
#pragma unroll
    for (int j = 0; j < 8; ++j) v[j] = bf16b(src[(size_t)j * H_DIM]);
    lds_b[f * 64 + l] = v;
  }

  // ---- partial c[b,h]: wave w covers e in [16w,16w+16); wave0 adds bias ----
  {
    const float* __restrict__ tg = target_item + b * 64;
    float cp = (w == 0) ? bias[l] : 0.0f;
#pragma unroll
    for (int e = 0; e < 16; ++e)
      cp = fmaf(tg[w * 16 + e], Wc[(w * 16 + e) * H_DIM + l], cp);
    c_part[w * 64 + l] = cp;
  }
  __syncthreads();

  s16x8 bfr[12];
#pragma unroll
  for (int f = 0; f < 12; ++f) bfr[f] = lds_b[f * 64 + l];

  float ch[4], zh[4];
#pragma unroll
  for (int nt = 0; nt < 4; ++nt) {
    const int h = nt * 16 + cc;
    ch[nt] = c_part[h] + c_part[64 + h] + c_part[128 + h] + c_part[192 + h];
    zh[nt] = z[h];
  }

  const float* __restrict__ itemsB = seq_items + (size_t)b * S_ * E_DIM;
  const float* __restrict__ posB = seq_pos + (size_t)b * S_ * P_DIM;

#pragma unroll
  for (int mt = 0; mt < 2; ++mt) {
    const int rb = s0 + w * 32 + mt * 16;  // row base of this 16-row M-tile
    const int s = rb + cc;                 // this lane's row (A: m = l&15)
    f32x4 acc[4] = {};                     // one C-frag per ntile

    // K-steps 0,1: items features [0..31], [32..63]
#pragma unroll
    for (int kk = 0; kk < 2; ++kk) {
      const float* __restrict__ p = itemsB + (size_t)s * E_DIM + kk * 32 + q * 8;
      const float4 x0 = ((const float4*)p)[0];
      const float4 x1 = ((const float4*)p)[1];
      s16x8 af;
      af[0] = bf16b(x0.x); af[1] = bf16b(x0.y);
      af[2] = bf16b(x0.z); af[3] = bf16b(x0.w);
      af[4] = bf16b(x1.x); af[5] = bf16b(x1.y);
      af[6] = bf16b(x1.z); af[7] = bf16b(x1.w);
#pragma unroll
      for (int nt = 0; nt < 4; ++nt)
        acc[nt] = __builtin_amdgcn_mfma_f32_16x16x32_bf16(af, bfr[kk * 4 + nt],
                                                          acc[nt], 0, 0, 0);
    }
    // K-step 2: pos features [0..31]
    {
      const float* __restrict__ p = posB + (size_t)s * P_DIM + q * 8;
      const float4 x0 = ((const float4*)p)[0];
      const float4 x1 = ((const float4*)p)[1];
      s16x8 af;
      af[0] = bf16b(x0.x); af[1] = bf16b(x0.y);
      af[2] = bf16b(x0.z); af[3] = bf16b(x0.w);
      af[4] = bf16b(x1.x); af[5] = bf16b(x1.y);
      af[6] = bf16b(x1.z); af[7] = bf16b(x1.w);
#pragma unroll
      for (int nt = 0; nt < 4; ++nt)
        acc[nt] = __builtin_amdgcn_mfma_f32_16x16x32_bf16(af, bfr[8 + nt],
                                                          acc[nt], 0, 0, 0);
    }

    // ---- epilogue: tanh + z, reduce over h (16 cols x 4 ntiles) ----
    float asum[4];
#pragma unroll
    for (int r = 0; r < 4; ++r) {
      float t = tanh_fast(acc[0][r] + ch[0]) * zh[0];
      t += tanh_fast(acc[1][r] + ch[1]) * zh[1];
      t += tanh_fast(acc[2][r] + ch[2]) * zh[2];
      t += tanh_fast(acc[3][r] + ch[3]) * zh[3];
      asum[r] = t;
    }
#pragma unroll
    for (int r = 0; r < 4; ++r) {
#pragma unroll
      for (int m = 8; m >= 1; m >>= 1) asum[r] += __shfl_xor(asum[r], m, 64);
    }
    if (cc == 0) {
#pragma unroll
      for (int r = 0; r < 4; ++r) s_a[w * 32 + mt * 16 + q * 4 + r] = asum[r];
    }
  }

  // ---- phase 3: chunk max / exp weights / sum-exp / raw-score sum ----
  __syncthreads();
  const int row = tid & 127;           // waves 2,3 duplicate rows of 0,1
  const int srow = s0 + row;
  const bool valid = uni || (srow < L);
  const float araw = s_a[row];
  const float ae = uni ? 0.0f : araw;  // uniform path: score 0 everywhere
  float mp = wave_reduce_max(valid ? ae : -INFINITY);
  if (l == 0) redm[w] = mp;
  __syncthreads();
  const float mc = fmaxf(fmaxf(redm[0], redm[1]), fmaxf(redm[2], redm[3]));
  const float wgt = valid ? __expf(ae - mc) : 0.0f;
  if (tid < 128) s_w[row] = wgt;
  const float scp = wave_reduce_sum(wgt);
  const float rap = wave_reduce_sum(valid ? ae : 0.0f);
  if (l == 0) { reds[w] = scp; redr[w] = rap; }
  __syncthreads();

  // ---- phase 4: pc[e] = sum_s w[s]*items[s,e] (items are L1/L2-hot) ----
  {
    const int e4 = l & 15;   // float4 column
    const int rr = l >> 4;   // row-group 0..3
    const float4* __restrict__ ip4 =
        (const float4*)(itemsB + (size_t)(s0 + w * 32) * E_DIM);
    float4 a4 = make_float4(0.f, 0.f, 0.f, 0.f);
#pragma unroll
    for (int i = 0; i < 8; ++i) {
      const int rloc = rr + i * 4;  // 0..31 within this wave's 32 rows
      const float g = s_w[w * 32 + rloc];
      const float4 x = ip4[rloc * 16 + e4];
      a4.x = fmaf(g, x.x, a4.x);
      a4.y = fmaf(g, x.y, a4.y);
      a4.z = fmaf(g, x.z, a4.z);
      a4.w = fmaf(g, x.w, a4.w);
    }
#pragma unroll
    for (int m = 16; m <= 32; m <<= 1) {
      a4.x += __shfl_xor(a4.x, m, 64);
      a4.y += __shfl_xor(a4.y, m, 64);
      a4.z += __shfl_xor(a4.z, m, 64);
      a4.w += __shfl_xor(a4.w, m, 64);
    }
    if (rr == 0) *(float4*)&s_pc[w * 64 + e4 * 4] = a4;
  }
  __syncthreads();

  float* __restrict__ cb = chunk_buf + (size_t)blk * CB_STRIDE;
  if (tid < 64) {
    cb[tid] = s_pc[tid] + s_pc[64 + tid] + s_pc[128 + tid] + s_pc[192 + tid];
  } else if (tid == 64) {
    cb[64] = mc;
  } else if (tid == 65) {
    cb[65] = reds[0] + reds[1];   // sc: waves 0,1 cover all 128 rows
  } else if (tid == 66) {
    cb[66] = redr[0] + redr[1];   // ra
  }
}

// ---------------------------------------------------------------------------
// K2: per-b combine of chunk partials (online-softmax merge).
//   m = max_c mc; u = sum_c pc*e^{mc-m} / sum_c sc*e^{mc-m}; r = sum_c ra.
// Grid: B_ blocks x 64 threads.
// ---------------------------------------------------------------------------
__global__ __launch_bounds__(64) void combine_kernel(
    const float* __restrict__ chunk_buf, const int* __restrict__ seq_len,
    float* __restrict__ out) {
  const int b = blockIdx.x;
  const int t = threadIdx.x;
  const int L = seq_len[b];
  const int nc = (L == 0) ? 16 : ((L + 127) >> 7);
  const float* __restrict__ cb = chunk_buf + (size_t)b * 16 * CB_STRIDE;

  float m = -INFINITY;
  for (int c = 0; c < nc; ++c) m = fmaxf(m, cb[c * CB_STRIDE + 64]);
  float u = 0.0f, den = 0.0f, r = 0.0f;
  for (int c = 0; c < nc; ++c) {
    const float e = __expf(cb[c * CB_STRIDE + 64] - m);
    u = fmaf(e, cb[c * CB_STRIDE + t], u);
    den = fmaf(e, cb[c * CB_STRIDE + 65], den);
    r += cb[c * CB_STRIDE + 66];
  }
  out[b * E_DIM + t] = u / den;
  if (t == 0) out[B_ * E_DIM + b] = r;
}

extern "C" void kernel_launch(void* const* d_in, const int* in_sizes, int n_in,
                              void* d_out, int out_size, void* d_ws, size_t ws_size,
                              hipStream_t stream) {
  const float* seq_items = (const float*)d_in[0];
  const float* seq_pos = (const float*)d_in[1];
  const float* target_item = (const float*)d_in[2];
  const float* Wp = (const float*)d_in[3];
  const float* We = (const float*)d_in[4];
  const float* Wc = (const float*)d_in[5];
  const float* Wc_ = Wc;
  const float* bias = (const float*)d_in[6];
  const float* z = (const float*)d_in[7];
  const int* seq_len = (const int*)d_in[8];
  float* out = (float*)d_out;
  float* chunk_buf = (float*)d_ws;  // B_*16*CB_STRIDE floats = 2.2 MB

  scores_mfma_kernel<<<B_ * 16, 256, 0, stream>>>(
      seq_items, seq_pos, target_item, Wp, We, Wc_, bias, z, seq_len, chunk_buf);
  combine_kernel<<<B_, 64, 0, stream>>>(chunk_buf, seq_len, out);
}

// Round 2
// 438.925 us; speedup vs baseline: 1.0659x; 1.0451x over previous
//
#include <hip/hip_runtime.h>
#include <hip/hip_bf16.h>
#include <math.h>

#define B_ 512
#define S_ 2048
#define E_DIM 64
#define P_DIM 32
#define H_DIM 64
#define CB_STRIDE 68  // 64 pc + mc + sc + ra + pad

typedef short s16x8 __attribute__((ext_vector_type(8)));
typedef int i32x4 __attribute__((ext_vector_type(4)));
typedef float f32x4 __attribute__((ext_vector_type(4)));

__device__ __forceinline__ float wave_reduce_sum(float v) {
#pragma unroll
  for (int m = 32; m >= 1; m >>= 1) v += __shfl_xor(v, m, 64);
  return v;
}

__device__ __forceinline__ float wave_reduce_max(float v) {
#pragma unroll
  for (int m = 32; m >= 1; m >>= 1) v = fmaxf(v, __shfl_xor(v, m, 64));
  return v;
}

__device__ __forceinline__ float tanh_fast(float x) {
  float e = __expf(2.0f * x);
  return 1.0f - 2.0f * __builtin_amdgcn_rcpf(e + 1.0f);
}

// fp32 -> bf16 bits with round-to-nearest-even (scalar; K0 only)
__device__ __forceinline__ short bf16b(float x) {
  union { float f; unsigned u; } a;
  a.f = x;
  unsigned r = (a.u + 0x7FFFu + ((a.u >> 16) & 1u)) >> 16;
  return (short)r;
}

// packed RNE convert: 2 fp32 -> 1 dword of 2 bf16 (v_cvt_pk_bf16_f32)
__device__ __forceinline__ int cvt_pk2(float a, float b) {
  union { __hip_bfloat162 v; int i; } u;
  u.v = __float22bfloat162_rn(make_float2(a, b));
  return u.i;
}

__device__ __forceinline__ s16x8 cvt8(float4 lo, float4 hi) {
  i32x4 r;
  r[0] = cvt_pk2(lo.x, lo.y);
  r[1] = cvt_pk2(lo.z, lo.w);
  r[2] = cvt_pk2(hi.x, hi.y);
  r[3] = cvt_pk2(hi.z, hi.w);
  return __builtin_bit_cast(s16x8, r);
}

// ---------------------------------------------------------------------------
// K0: per-launch precompute (b-independent / small):
//   block 0: 12 bf16 B-fragments of [We;Wp] -> frags (12 KB, MFMA layout)
//   blocks 1..128: c_all[b,h] = bias[h] + sum_e target[b,e]*Wc[e,h]
// ---------------------------------------------------------------------------
__global__ __launch_bounds__(256) void precompute_kernel(
    const float* __restrict__ target_item, const float* __restrict__ Wp,
    const float* __restrict__ We, const float* __restrict__ Wc,
    const float* __restrict__ bias, s16x8* __restrict__ frags,
    float* __restrict__ c_all) {
  const int tid = threadIdx.x;
  const int l = tid & 63;
  if (blockIdx.x == 0) {
    const int w = tid >> 6;
    const int cc = l & 15;
    const int q = l >> 4;
#pragma unroll
    for (int i = 0; i < 3; ++i) {
      const int f = w * 3 + i;
      const int kstep = f >> 2;
      const int nt = f & 3;
      const float* __restrict__ src =
          (kstep < 2)
              ? (We + (size_t)(kstep * 32 + q * 8) * H_DIM + nt * 16 + cc)
              : (Wp + (size_t)(q * 8) * H_DIM + nt * 16 + cc);
      s16x8 v;
#pragma unroll
      for (int j = 0; j < 8; ++j) v[j] = bf16b(src[(size_t)j * H_DIM]);
      frags[f * 64 + l] = v;
    }
  } else {
    const int b = (blockIdx.x - 1) * 4 + (tid >> 6);
    const int h = l;
    const float* __restrict__ tg = target_item + b * E_DIM;
    float c = bias[h];
#pragma unroll
    for (int e = 0; e < 64; ++e) c = fmaf(tg[e], Wc[e * H_DIM + h], c);
    c_all[b * H_DIM + h] = c;
  }
}

// ---------------------------------------------------------------------------
// K1 (MFMA + fused chunk-softmax partials), lean prologue version:
//   - B fragments read global->VGPR (L2-hot), no LDS build, no barrier
//   - c[b,:] read from c_all (K0), no per-block recompute
//   - all 12 item/pos float4 loads issued up front, packed bf16 convert
//   then per 128-row chunk: mc, sc = sum exp(a-mc), pc = sum exp*items, ra.
//   L==0: uniform path (all rows valid, a=0, ra forced 0).
// ---------------------------------------------------------------------------
__global__ __launch_bounds__(256) void scores_mfma_kernel(
    const float* __restrict__ seq_items, const float* __restrict__ seq_pos,
    const float* __restrict__ z, const int* __restrict__ seq_len,
    const s16x8* __restrict__ frags, const float* __restrict__ c_all,
    float* __restrict__ chunk_buf) {
  const int blk = blockIdx.x;
  const int b = blk >> 4;          // 16 chunks of 128 positions per b
  const int s0 = (blk & 15) << 7;
  const int L = seq_len[b];
  const bool uni = (L == 0);
  if (!uni && s0 >= L) return;  // combine kernel never reads these chunks

  __shared__ float s_a[128];                // raw scores of this chunk
  __shared__ float s_w[128];                // exp(a - mc)
  __shared__ __align__(16) float s_pc[4 * 64];  // per-wave weighted item sums
  __shared__ float redm[4], reds[4], redr[4];

  const int tid = threadIdx.x;
  const int l = tid & 63;
  const int w = tid >> 6;
  const int cc = l & 15;  // col within 16 (n / h-within-tile; also row m for A)
  const int q = l >> 4;   // quad -> k-chunk (and row-group for C/D)

  // ---- B fragments: straight from global (L2-hot after first blocks) ----
  s16x8 bfr[12];
#pragma unroll
  for (int f = 0; f < 12; ++f) bfr[f] = frags[f * 64 + l];

  float ch[4], zh[4];
#pragma unroll
  for (int nt = 0; nt < 4; ++nt) {
    const int h = nt * 16 + cc;
    ch[nt] = c_all[b * H_DIM + h];
    zh[nt] = z[h];
  }

  const float* __restrict__ itemsB = seq_items + (size_t)b * S_ * E_DIM;
  const float* __restrict__ posB = seq_pos + (size_t)b * S_ * P_DIM;

  // ---- issue ALL A-operand loads up front (12 x float4 per lane) ----
  float4 xi[2][4];  // [mt][kk*2+half]
  float4 xp[2][2];  // [mt][half]
#pragma unroll
  for (int mt = 0; mt < 2; ++mt) {
    const int s = s0 + w * 32 + mt * 16 + cc;  // this lane's row (A: m = l&15)
    const float* __restrict__ pi = itemsB + (size_t)s * E_DIM + q * 8;
    xi[mt][0] = ((const float4*)pi)[0];
    xi[mt][1] = ((const float4*)pi)[1];
    xi[mt][2] = ((const float4*)(pi + 32))[0];
    xi[mt][3] = ((const float4*)(pi + 32))[1];
    const float* __restrict__ pp = posB + (size_t)s * P_DIM + q * 8;
    xp[mt][0] = ((const float4*)pp)[0];
    xp[mt][1] = ((const float4*)pp)[1];
  }

  // ---- packed bf16 convert (v_cvt_pk_bf16_f32) ----
  s16x8 afr[2][3];
#pragma unroll
  for (int mt = 0; mt < 2; ++mt) {
    afr[mt][0] = cvt8(xi[mt][0], xi[mt][1]);
    afr[mt][1] = cvt8(xi[mt][2], xi[mt][3]);
    afr[mt][2] = cvt8(xp[mt][0], xp[mt][1]);
  }

#pragma unroll
  for (int mt = 0; mt < 2; ++mt) {
    f32x4 acc[4] = {};  // one C-frag per ntile
#pragma unroll
    for (int kk = 0; kk < 2; ++kk) {
#pragma unroll
      for (int nt = 0; nt < 4; ++nt)
        acc[nt] = __builtin_amdgcn_mfma_f32_16x16x32_bf16(
            afr[mt][kk], bfr[kk * 4 + nt], acc[nt], 0, 0, 0);
    }
#pragma unroll
    for (int nt = 0; nt < 4; ++nt)
      acc[nt] = __builtin_amdgcn_mfma_f32_16x16x32_bf16(
          afr[mt][2], bfr[8 + nt], acc[nt], 0, 0, 0);

    // ---- epilogue: tanh + z, reduce over h (16 cols x 4 ntiles) ----
    float asum[4];
#pragma unroll
    for (int r = 0; r < 4; ++r) {
      float t = tanh_fast(acc[0][r] + ch[0]) * zh[0];
      t += tanh_fast(acc[1][r] + ch[1]) * zh[1];
      t += tanh_fast(acc[2][r] + ch[2]) * zh[2];
      t += tanh_fast(acc[3][r] + ch[3]) * zh[3];
      asum[r] = t;
    }
#pragma unroll
    for (int r = 0; r < 4; ++r) {
#pragma unroll
      for (int m = 8; m >= 1; m >>= 1) asum[r] += __shfl_xor(asum[r], m, 64);
    }
    if (cc == 0) {
#pragma unroll
      for (int r = 0; r < 4; ++r) s_a[w * 32 + mt * 16 + q * 4 + r] = asum[r];
    }
  }

  // ---- phase 3: chunk max / exp weights / sum-exp / raw-score sum ----
  __syncthreads();
  const int row = tid & 127;           // waves 2,3 duplicate rows of 0,1
  const int srow = s0 + row;
  const bool valid = uni || (srow < L);
  const float araw = s_a[row];
  const float ae = uni ? 0.0f : araw;  // uniform path: score 0 everywhere
  float mp = wave_reduce_max(valid ? ae : -INFINITY);
  if (l == 0) redm[w] = mp;
  __syncthreads();
  const float mc = fmaxf(fmaxf(redm[0], redm[1]), fmaxf(redm[2], redm[3]));
  const float wgt = valid ? __expf(ae - mc) : 0.0f;
  if (tid < 128) s_w[row] = wgt;
  const float scp = wave_reduce_sum(wgt);
  const float rap = wave_reduce_sum(valid ? ae : 0.0f);
  if (l == 0) { reds[w] = scp; redr[w] = rap; }
  __syncthreads();

  // ---- phase 4: pc[e] = sum_s w[s]*items[s,e] (items are L1/L2-hot) ----
  {
    const int e4 = l & 15;   // float4 column
    const int rr = l >> 4;   // row-group 0..3
    const float4* __restrict__ ip4 =
        (const float4*)(itemsB + (size_t)(s0 + w * 32) * E_DIM);
    float4 a4 = make_float4(0.f, 0.f, 0.f, 0.f);
#pragma unroll
    for (int i = 0; i < 8; ++i) {
      const int rloc = rr + i * 4;  // 0..31 within this wave's 32 rows
      const float g = s_w[w * 32 + rloc];
      const float4 x = ip4[rloc * 16 + e4];
      a4.x = fmaf(g, x.x, a4.x);
      a4.y = fmaf(g, x.y, a4.y);
      a4.z = fmaf(g, x.z, a4.z);
      a4.w = fmaf(g, x.w, a4.w);
    }
#pragma unroll
    for (int m = 16; m <= 32; m <<= 1) {
      a4.x += __shfl_xor(a4.x, m, 64);
      a4.y += __shfl_xor(a4.y, m, 64);
      a4.z += __shfl_xor(a4.z, m, 64);
      a4.w += __shfl_xor(a4.w, m, 64);
    }
    if (rr == 0) *(float4*)&s_pc[w * 64 + e4 * 4] = a4;
  }
  __syncthreads();

  float* __restrict__ cb = chunk_buf + (size_t)blk * CB_STRIDE;
  if (tid < 64) {
    cb[tid] = s_pc[tid] + s_pc[64 + tid] + s_pc[128 + tid] + s_pc[192 + tid];
  } else if (tid == 64) {
    cb[64] = mc;
  } else if (tid == 65) {
    cb[65] = reds[0] + reds[1];   // sc: waves 0,1 cover all 128 rows
  } else if (tid == 66) {
    cb[66] = redr[0] + redr[1];   // ra
  }
}

// ---------------------------------------------------------------------------
// K2: per-b combine of chunk partials (online-softmax merge).
//   m = max_c mc; u = sum_c pc*e^{mc-m} / sum_c sc*e^{mc-m}; r = sum_c ra.
// Grid: B_ blocks x 64 threads.
// ---------------------------------------------------------------------------
__global__ __launch_bounds__(64) void combine_kernel(
    const float* __restrict__ chunk_buf, const int* __restrict__ seq_len,
    float* __restrict__ out) {
  const int b = blockIdx.x;
  const int t = threadIdx.x;
  const int L = seq_len[b];
  const int nc = (L == 0) ? 16 : ((L + 127) >> 7);
  const float* __restrict__ cb = chunk_buf + (size_t)b * 16 * CB_STRIDE;

  float m = -INFINITY;
  for (int c = 0; c < nc; ++c) m = fmaxf(m, cb[c * CB_STRIDE + 64]);
  float u = 0.0f, den = 0.0f, r = 0.0f;
  for (int c = 0; c < nc; ++c) {
    const float e = __expf(cb[c * CB_STRIDE + 64] - m);
    u = fmaf(e, cb[c * CB_STRIDE + t], u);
    den = fmaf(e, cb[c * CB_STRIDE + 65], den);
    r += cb[c * CB_STRIDE + 66];
  }
  out[b * E_DIM + t] = u / den;
  if (t == 0) out[B_ * E_DIM + b] = r;
}

extern "C" void kernel_launch(void* const* d_in, const int* in_sizes, int n_in,
                              void* d_out, int out_size, void* d_ws, size_t ws_size,
                              hipStream_t stream) {
  const float* seq_items = (const float*)d_in[0];
  const float* seq_pos = (const float*)d_in[1];
  const float* target_item = (const float*)d_in[2];
  const float* Wp = (const float*)d_in[3];
  const float* We = (const float*)d_in[4];
  const float* Wc = (const float*)d_in[5];
  const float* bias = (const float*)d_in[6];
  const float* z = (const float*)d_in[7];
  const int* seq_len = (const int*)d_in[8];
  float* out = (float*)d_out;

  // workspace layout (floats): chunk_buf[8192*68] | c_all[512*64] | frags
  float* chunk_buf = (float*)d_ws;
  float* c_all = (float*)d_ws + (size_t)B_ * 16 * CB_STRIDE;
  s16x8* frags =
      (s16x8*)((float*)d_ws + (size_t)B_ * 16 * CB_STRIDE + B_ * H_DIM);

  precompute_kernel<<<129, 256, 0, stream>>>(target_item, Wp, We, Wc, bias,
                                             frags, c_all);
  scores_mfma_kernel<<<B_ * 16, 256, 0, stream>>>(seq_items, seq_pos, z,
                                                  seq_len, frags, c_all,
                                                  chunk_buf);
  combine_kernel<<<B_, 64, 0, stream>>>(chunk_buf, seq_len, out);
}